// Round 6
// baseline (109.043 us; speedup 1.0000x reference)
//
#include <hip/hip_runtime.h>
#include <hip/hip_bf16.h>

typedef __attribute__((ext_vector_type(8))) short short8;
typedef __attribute__((ext_vector_type(4))) float f32x4;

#define LDSW 136        // padded row stride (bf16 elems) = 272 B
#define CS_BLOCKS 1250  // 1250 blocks x 5120 float4 contiguous = 6,400,000 exact (20/thread)

// round-to-nearest-even f32 -> bf16
static __device__ __forceinline__ ushort f2bf(float f) {
  unsigned int u = __builtin_bit_cast(unsigned int, f);
  u += 0x7fffu + ((u >> 16) & 1u);
  return (ushort)(u >> 16);
}

static __device__ __forceinline__ ushort4 pack4(float4 v) {
  ushort4 r;
  r.x = f2bf(v.x); r.y = f2bf(v.y); r.z = f2bf(v.z); r.w = f2bf(v.w);
  return r;
}

// ---------------- kernel 1: pack w1 (f32 row-major) -> bf16 [col][k] with padded stride ----
__global__ __launch_bounds__(256) void pack_w1_kernel(const float* __restrict__ w1,
                                                      ushort* __restrict__ w1p) {
  int tid = blockIdx.x * 256 + threadIdx.x;
  int k = tid >> 7;
  int c = tid & 127;
  w1p[c * LDSW + k] = f2bf(w1[k * 128 + c]);
}

// ---------------- kernel 2: colsum + bf16 stash (store-paired read stream) -----------------
// Theory: pure-read-to-VGPR streams plateau ~1.8 TB/s on this part; every demonstrated-fast
// pattern pairs reads with stores (copy 6.3 TB/s agg) or bypasses VGPRs. So pair the colsum
// read with a USEFUL store: write bf16(x) to ws for the gemm (halves gemm's read + kills its
// inner-loop convert). Contiguous 81,920-B chunk per block, 20 float4/thread, exact fit.
__global__ __launch_bounds__(256) void colsum_stash_kernel(const float4* __restrict__ x4,
                                                           ushort4* __restrict__ stash4,
                                                           float4* __restrict__ partial4) {
  __shared__ float4 red[8][32];  // 4 KB
  int tid = threadIdx.x;
  const float4* bb = x4 + (size_t)blockIdx.x * 5120;
  ushort4* sb = stash4 + (size_t)blockIdx.x * 5120;
  float4 acc = {0.f, 0.f, 0.f, 0.f};
#pragma unroll
  for (int kb = 0; kb < 5; ++kb) {
    int i0 = kb * 1024 + tid;
    float4 v0 = bb[i0];
    float4 v1 = bb[i0 + 256];
    float4 v2 = bb[i0 + 512];
    float4 v3 = bb[i0 + 768];
    sb[i0]       = pack4(v0);
    sb[i0 + 256] = pack4(v1);
    sb[i0 + 512] = pack4(v2);
    sb[i0 + 768] = pack4(v3);
    acc.x += v0.x + v1.x + v2.x + v3.x;
    acc.y += v0.y + v1.y + v2.y + v3.y;
    acc.z += v0.z + v1.z + v2.z + v3.z;
    acc.w += v0.w + v1.w + v2.w + v3.w;
  }
  red[tid >> 5][tid & 31] = acc;
  __syncthreads();
  if (tid < 32) {
    float4 s = red[0][tid];
#pragma unroll
    for (int g = 1; g < 8; ++g) {
      float4 v = red[g][tid];
      s.x += v.x; s.y += v.y; s.z += v.z; s.w += v.w;
    }
    partial4[blockIdx.x * 32 + tid] = s;
  }
}

// ---------------- kernel 3: t = (pooled @ w2)/n + bias  (1 block x 1024 thr) ---------------
__global__ __launch_bounds__(1024) void transmit_kernel(const float* __restrict__ partial,
                                                        const float* __restrict__ w2,
                                                        const float* __restrict__ bias,
                                                        float* __restrict__ t, int n,
                                                        int nblocks) {
  __shared__ float red[8][128];
  __shared__ float pooled[128];
  int tid = threadIdx.x;
  int j = tid & 127;
  int g = tid >> 7;

  float s = 0.f;
  for (int b = g; b < nblocks; b += 8) s += partial[b * 128 + j];
  red[g][j] = s;
  __syncthreads();
  if (tid < 128) {
    float p = 0.f;
#pragma unroll
    for (int gg = 0; gg < 8; ++gg) p += red[gg][j];
    pooled[j] = p;
  }
  __syncthreads();

  float acc = 0.f;
#pragma unroll
  for (int ii = 0; ii < 16; ++ii) {
    int i = g * 16 + ii;
    acc += pooled[i] * w2[i * 128 + j];
  }
  __syncthreads();
  red[g][j] = acc;
  __syncthreads();
  if (tid < 128) {
    float a = 0.f;
#pragma unroll
    for (int gg = 0; gg < 8; ++gg) a += red[gg][j];
    t[j] = a / (float)n + bias[j];
  }
}

// ---------------- kernel 4: out = bf16stash @ w1 + t  (MFMA, no inner convert) -------------
__global__ __launch_bounds__(256) void gemm_kernel(const ushort* __restrict__ xb,
                                                   const ushort* __restrict__ w1p,
                                                   const float* __restrict__ tvec,
                                                   float* __restrict__ out) {
  __shared__ ushort w1t[128 * LDSW];
  __shared__ float t_lds[128];
  int tid = threadIdx.x;

  {
    const ulonglong2* src = reinterpret_cast<const ulonglong2*>(w1p);
    ulonglong2* dst = reinterpret_cast<ulonglong2*>(w1t);
#pragma unroll
    for (int i = 0; i < (128 * LDSW * 2) / 16 / 256 + 1; ++i) {
      int idx = tid + i * 256;
      if (idx < (128 * LDSW * 2) / 16) dst[idx] = src[idx];
    }
  }
  if (tid < 128) t_lds[tid] = tvec[tid];
  __syncthreads();

  int lane = tid & 63;
  int wave = tid >> 6;
  int c = lane & 15;    // A row-in-tile / B col / D col
  int kg = lane >> 4;   // k-group 0..3
  int rbase = blockIdx.x * 64 + wave * 16;
  const ushort* xrow = xb + (size_t)(rbase + c) * 128;

  f32x4 acc[8];
#pragma unroll
  for (int nb = 0; nb < 8; ++nb) acc[nb] = (f32x4){0.f, 0.f, 0.f, 0.f};

#pragma unroll
  for (int kb = 0; kb < 4; ++kb) {
    int k0 = kb * 32 + kg * 8;
    short8 afrag = *reinterpret_cast<const short8*>(xrow + k0);  // 16B direct bf16 load
#pragma unroll
    for (int nb = 0; nb < 8; ++nb) {
      short8 bfrag = *reinterpret_cast<const short8*>(&w1t[(nb * 16 + c) * LDSW + k0]);
      acc[nb] = __builtin_amdgcn_mfma_f32_16x16x32_bf16(afrag, bfrag, acc[nb], 0, 0, 0);
    }
  }

  // D layout (m89-verified): col = lane&15, row = (lane>>4)*4 + reg
#pragma unroll
  for (int nb = 0; nb < 8; ++nb) {
    int col = nb * 16 + c;
    float tv = t_lds[col];
#pragma unroll
    for (int i = 0; i < 4; ++i) {
      out[(size_t)(rbase + kg * 4 + i) * 128 + col] = acc[nb][i] + tv;
    }
  }
}

extern "C" void kernel_launch(void* const* d_in, const int* in_sizes, int n_in,
                              void* d_out, int out_size, void* d_ws, size_t ws_size,
                              hipStream_t stream) {
  const float* x = (const float*)d_in[0];
  const float* w1 = (const float*)d_in[1];
  const float* w2 = (const float*)d_in[2];
  const float* bias = (const float*)d_in[3];
  float* out = (float*)d_out;
  int n = in_sizes[0] / 128;  // 200000

  char* ws = (char*)d_ws;
  float* t = (float*)ws;                          // 512 B
  ushort* w1p = (ushort*)(ws + 512);              // 34,816 B -> ends 35,328
  float* partial = (float*)(ws + 35328);          // 1250*128*4 = 640,000 B -> ends 675,328
  ushort* stash = (ushort*)(ws + 675328);         // 25.6M bf16 = 51,200,000 B

  hipLaunchKernelGGL(pack_w1_kernel, dim3(64), dim3(256), 0, stream, w1, w1p);
  hipLaunchKernelGGL(colsum_stash_kernel, dim3(CS_BLOCKS), dim3(256), 0, stream,
                     (const float4*)x, (ushort4*)stash, (float4*)partial);
  hipLaunchKernelGGL(transmit_kernel, dim3(1), dim3(1024), 0, stream,
                     partial, w2, bias, t, n, CS_BLOCKS);
  hipLaunchKernelGGL(gemm_kernel, dim3(n / 64), dim3(256), 0, stream, stash, w1p, t, out);
}

// Round 7
// 89.882 us; speedup vs baseline: 1.2132x; 1.2132x over previous
//
#include <hip/hip_runtime.h>
#include <hip/hip_bf16.h>

typedef __attribute__((ext_vector_type(8))) short short8;
typedef __attribute__((ext_vector_type(4))) float f32x4;

#define LDSW 136       // padded row stride (bf16 elems) = 272 B
#define CS_BLOCKS 625  // 625 blocks x 5 tiles x 64 rows = 200000 exact

// round-to-nearest-even f32 -> bf16
static __device__ __forceinline__ ushort f2bf(float f) {
  unsigned int u = __builtin_bit_cast(unsigned int, f);
  u += 0x7fffu + ((u >> 16) & 1u);
  return (ushort)(u >> 16);
}

// ---------------- kernel 1: pack w1 (f32 row-major) -> bf16 [col][k] with padded stride ----
__global__ __launch_bounds__(256) void pack_w1_kernel(const float* __restrict__ w1,
                                                      ushort* __restrict__ w1p) {
  int tid = blockIdx.x * 256 + threadIdx.x;
  int k = tid >> 7;
  int c = tid & 127;
  w1p[c * LDSW + k] = f2bf(w1[k * 128 + c]);
}

// ---------------- kernel 2: column-sum, gemm-shaped access pattern -------------------------
// Ledger across R2-R6: every contiguous/strided colsum = 60-65µs (1.65 TB/s) regardless of
// occupancy (4-32 waves/CU) and ILP (1-5 deep). The gemm kernel reads the same 102.4MB in
// ~15µs. Its distinguishing feature: each wave-load touches 16 DIFFERENT rows (512B stride)
// in 16-32B segments, engaging many L2/L3 interleave slices concurrently, vs colsum's
// contiguous 1KB wave-loads serializing on few slices. This kernel replicates that pattern:
//   thread t: rc = t&15 (rows rc*4..rc*4+3 of each tile), co = t>>4 (cols co*8..co*8+7)
//   -> per load instruction, 16 lanes hit 16 rows 2KB apart: maximal slice scatter.
// Cols are thread-fixed so 20 rows accumulate in registers; cross-row reduce is a 4-step
// shfl_xor butterfly over the 16-lane group (no LDS, no barrier); lanes l%16==0 store.
__global__ __launch_bounds__(256) void colsum_gs_kernel(const float* __restrict__ x,
                                                        float* __restrict__ partial) {
  int tid = threadIdx.x;
  int rc = tid & 15;   // row-chunk
  int co = tid >> 4;   // col-octet
  const float* base = x + (size_t)blockIdx.x * (5 * 64 * 128) + co * 8;

  f32x4 s0 = {0.f, 0.f, 0.f, 0.f}, s1 = {0.f, 0.f, 0.f, 0.f};
#pragma unroll
  for (int tau = 0; tau < 5; ++tau) {
#pragma unroll
    for (int i = 0; i < 4; ++i) {
      const float* p = base + (size_t)(tau * 64 + rc * 4 + i) * 128;
      float4 u0 = *reinterpret_cast<const float4*>(p);
      float4 u1 = *reinterpret_cast<const float4*>(p + 4);
      s0.x += u0.x; s0.y += u0.y; s0.z += u0.z; s0.w += u0.w;
      s1.x += u1.x; s1.y += u1.y; s1.z += u1.z; s1.w += u1.w;
    }
  }
  // butterfly over the 16 row-chunks (lanes sharing co)
#pragma unroll
  for (int m = 8; m >= 1; m >>= 1) {
    s0.x += __shfl_xor(s0.x, m, 16);
    s0.y += __shfl_xor(s0.y, m, 16);
    s0.z += __shfl_xor(s0.z, m, 16);
    s0.w += __shfl_xor(s0.w, m, 16);
    s1.x += __shfl_xor(s1.x, m, 16);
    s1.y += __shfl_xor(s1.y, m, 16);
    s1.z += __shfl_xor(s1.z, m, 16);
    s1.w += __shfl_xor(s1.w, m, 16);
  }
  if ((tid & 15) == 0) {
    f32x4* dst = reinterpret_cast<f32x4*>(partial + (size_t)blockIdx.x * 128 + co * 8);
    dst[0] = s0;
    dst[1] = s1;
  }
}

// ---------------- kernel 3: t = (pooled @ w2)/n + bias  (1 block x 1024 thr) ---------------
__global__ __launch_bounds__(1024) void transmit_kernel(const float* __restrict__ partial,
                                                        const float* __restrict__ w2,
                                                        const float* __restrict__ bias,
                                                        float* __restrict__ t, int n,
                                                        int nblocks) {
  __shared__ float red[8][128];
  __shared__ float pooled[128];
  int tid = threadIdx.x;
  int j = tid & 127;
  int g = tid >> 7;

  float s = 0.f;
  for (int b = g; b < nblocks; b += 8) s += partial[b * 128 + j];
  red[g][j] = s;
  __syncthreads();
  if (tid < 128) {
    float p = 0.f;
#pragma unroll
    for (int gg = 0; gg < 8; ++gg) p += red[gg][j];
    pooled[j] = p;
  }
  __syncthreads();

  float acc = 0.f;
#pragma unroll
  for (int ii = 0; ii < 16; ++ii) {
    int i = g * 16 + ii;
    acc += pooled[i] * w2[i * 128 + j];
  }
  __syncthreads();
  red[g][j] = acc;
  __syncthreads();
  if (tid < 128) {
    float a = 0.f;
#pragma unroll
    for (int gg = 0; gg < 8; ++gg) a += red[gg][j];
    t[j] = a / (float)n + bias[j];
  }
}

// ---------------- kernel 4: out = x @ w1 + t  (bf16 MFMA, f32 accumulate) ------------------
__global__ __launch_bounds__(256) void gemm_kernel(const float* __restrict__ x,
                                                   const ushort* __restrict__ w1p,
                                                   const float* __restrict__ tvec,
                                                   float* __restrict__ out) {
  __shared__ ushort w1t[128 * LDSW];
  __shared__ float t_lds[128];
  int tid = threadIdx.x;

  {
    const ulonglong2* src = reinterpret_cast<const ulonglong2*>(w1p);
    ulonglong2* dst = reinterpret_cast<ulonglong2*>(w1t);
#pragma unroll
    for (int i = 0; i < (128 * LDSW * 2) / 16 / 256 + 1; ++i) {
      int idx = tid + i * 256;
      if (idx < (128 * LDSW * 2) / 16) dst[idx] = src[idx];
    }
  }
  if (tid < 128) t_lds[tid] = tvec[tid];
  __syncthreads();

  int lane = tid & 63;
  int wave = tid >> 6;
  int c = lane & 15;    // A row-in-tile / B col / D col
  int kg = lane >> 4;   // k-group 0..3
  int rbase = blockIdx.x * 64 + wave * 16;
  const float* xrow = x + (size_t)(rbase + c) * 128;

  f32x4 acc[8];
#pragma unroll
  for (int nb = 0; nb < 8; ++nb) acc[nb] = (f32x4){0.f, 0.f, 0.f, 0.f};

#pragma unroll
  for (int kb = 0; kb < 4; ++kb) {
    int k0 = kb * 32 + kg * 8;
    float4 a0 = *reinterpret_cast<const float4*>(xrow + k0);
    float4 a1 = *reinterpret_cast<const float4*>(xrow + k0 + 4);
    short8 afrag;
    afrag[0] = (short)f2bf(a0.x);
    afrag[1] = (short)f2bf(a0.y);
    afrag[2] = (short)f2bf(a0.z);
    afrag[3] = (short)f2bf(a0.w);
    afrag[4] = (short)f2bf(a1.x);
    afrag[5] = (short)f2bf(a1.y);
    afrag[6] = (short)f2bf(a1.z);
    afrag[7] = (short)f2bf(a1.w);
#pragma unroll
    for (int nb = 0; nb < 8; ++nb) {
      short8 bfrag = *reinterpret_cast<const short8*>(&w1t[(nb * 16 + c) * LDSW + k0]);
      acc[nb] = __builtin_amdgcn_mfma_f32_16x16x32_bf16(afrag, bfrag, acc[nb], 0, 0, 0);
    }
  }

  // D layout (m89-verified): col = lane&15, row = (lane>>4)*4 + reg
#pragma unroll
  for (int nb = 0; nb < 8; ++nb) {
    int col = nb * 16 + c;
    float tv = t_lds[col];
#pragma unroll
    for (int i = 0; i < 4; ++i) {
      out[(size_t)(rbase + kg * 4 + i) * 128 + col] = acc[nb][i] + tv;
    }
  }
}

extern "C" void kernel_launch(void* const* d_in, const int* in_sizes, int n_in,
                              void* d_out, int out_size, void* d_ws, size_t ws_size,
                              hipStream_t stream) {
  const float* x = (const float*)d_in[0];
  const float* w1 = (const float*)d_in[1];
  const float* w2 = (const float*)d_in[2];
  const float* bias = (const float*)d_in[3];
  float* out = (float*)d_out;
  int n = in_sizes[0] / 128;  // 200000

  char* ws = (char*)d_ws;
  float* t = (float*)ws;                   // 512 B
  ushort* w1p = (ushort*)(ws + 512);       // 34,816 B -> ends 35,328
  float* partial = (float*)(ws + 35328);   // 625*128*4 = 320,000 B

  hipLaunchKernelGGL(pack_w1_kernel, dim3(64), dim3(256), 0, stream, w1, w1p);
  hipLaunchKernelGGL(colsum_gs_kernel, dim3(CS_BLOCKS), dim3(256), 0, stream, x, partial);
  hipLaunchKernelGGL(transmit_kernel, dim3(1), dim3(1024), 0, stream,
                     partial, w2, bias, t, n, CS_BLOCKS);
  hipLaunchKernelGGL(gemm_kernel, dim3(n / 64), dim3(256), 0, stream, x, w1p, t, out);
}